// Round 7
// baseline (851.212 us; speedup 1.0000x reference)
//
#include <hip/hip_runtime.h>

typedef unsigned short u16;
typedef unsigned int u32;
typedef __attribute__((ext_vector_type(8))) short v8s;
typedef __attribute__((ext_vector_type(4))) float f32x4;

#define RPB 128            // rows per block (4 waves x 32 rows)
#define THREADS 256
#define NSB 512            // sort blocks (512 x 512 threads = 262144)
// u16 offsets inside Wf
#define W1F 0
#define W2F 8192
#define W3F 73728
#define W4F 139264
#define TOTW 143360
// workspace byte offsets
#define BH_OFF 286720      // blockHist: NSB*9*4 = 18432 B
#define PERM_OFF 305152    // perm: B*4

#define MFMA(w, b, c) __builtin_amdgcn_mfma_f32_16x16x32_bf16((w), (b), (c), 0, 0, 0)
#define SGB __builtin_amdgcn_sched_group_barrier
#define M_DS 0x100         // DS_READ
#define M_MFMA 0x8

typedef __attribute__((address_space(1))) const unsigned int gu32;
typedef __attribute__((address_space(3))) unsigned int su32;
__device__ __forceinline__ void gld16(const u16* g, u16* l) {
  __builtin_amdgcn_global_load_lds((gu32*)g, (su32*)l, 16, 0, 0);
}

__device__ __forceinline__ u32 pk2(float a, float b) {
  u32 r;
  asm("v_cvt_pk_bf16_f32 %0, %1, %2" : "=v"(r) : "v"(a), "v"(b));
  return r;
}
__device__ __forceinline__ float bfu(u32 w, int hi) {   // bf16 half -> f32
  return __uint_as_float(hi ? (w & 0xffff0000u) : (w << 16));
}
__device__ __forceinline__ f32x4 silu4(f32x4 v) {
  f32x4 r;
#pragma unroll
  for (int i = 0; i < 4; ++i) r[i] = v[i] * __builtin_amdgcn_rcpf(1.0f + __expf(-v[i]));
  return r;
}

// ---------------------------------------------------------------------------
// Weight prep: bf16, A-fragment order (lane l holds A[m=l&15][k-slot q*8+j]),
// with the k-slot permutation  slot(q,j) <-> feature f = 32ks+16*(j>>2)+4q+(j&3).
// W1: K padded 12->32 (rows 6..11 duplicate 0..5 for the hi/lo input split).
// W4: out-features padded 4->16. W2/W3 stored slice-major: (ks*16+mt)*512.
// ---------------------------------------------------------------------------
__global__ void prep_weights(const float* __restrict__ W1, const float* __restrict__ W2,
                             const float* __restrict__ W3, const float* __restrict__ W4,
                             u16* __restrict__ Wf) {
  int e = blockIdx.x * 256 + threadIdx.x;
  if (e >= TOTW) return;
  float val = 0.0f;
  if (e < W2F) {
    int mt = e >> 9, idx = e & 511, l = idx >> 3, j = idx & 7;
    int q = l >> 4, m = l & 15;
    int f = 16 * (j >> 2) + 4 * q + (j & 3);
    int col = mt * 16 + m;
    val = (f < 6) ? W1[f * 256 + col] : ((f < 12) ? W1[(f - 6) * 256 + col] : 0.0f);
  } else if (e < W3F) {
    int e2 = e - W2F, blk = e2 >> 9, idx = e2 & 511, l = idx >> 3, j = idx & 7;
    int ks = blk >> 4, mt = blk & 15, q = l >> 4, m = l & 15;
    int f = 32 * ks + 16 * (j >> 2) + 4 * q + (j & 3);
    val = W2[f * 256 + mt * 16 + m];
  } else if (e < W4F) {
    int e2 = e - W3F, blk = e2 >> 9, idx = e2 & 511, l = idx >> 3, j = idx & 7;
    int ks = blk >> 4, mt = blk & 15, q = l >> 4, m = l & 15;
    int f = 32 * ks + 16 * (j >> 2) + 4 * q + (j & 3);
    val = W3[f * 256 + mt * 16 + m];
  } else {
    int e2 = e - W4F, ks = e2 >> 9, idx = e2 & 511, l = idx >> 3, j = idx & 7;
    int q = l >> 4, m = l & 15;
    int f = 32 * ks + 16 * (j >> 2) + 4 * q + (j & 3);
    val = (m < 4) ? W4[f * 4 + m] : 0.0f;
  }
  Wf[e] = (u16)pk2(val, val);
}

// ------------------ counting sort by n_full (LDS-local, no global atomics) --
__global__ void hist_blocks(const float* __restrict__ zf, int* __restrict__ bh, int B) {
  __shared__ int h[9];
  int t = threadIdx.x;
  if (t < 9) h[t] = 0;
  __syncthreads();
  int r = blockIdx.x * 512 + t;
  if (r < B) {
    int nf = min(max((int)floorf(zf[r] * 8.0f), 0), 8);
    atomicAdd(&h[nf], 1);
  }
  __syncthreads();
  if (t < 9) bh[blockIdx.x * 9 + t] = h[t];
}

__global__ void scan_offsets(int* __restrict__ bh) {
  __shared__ int S[NSB * 9];
  __shared__ int tot[9], ebase[9];
  int t = threadIdx.x;
  for (int i = t; i < NSB * 9; i += 512) S[i] = bh[i];
  __syncthreads();
  if (t < 9) {
    int s = 0;
    for (int b = 0; b < NSB; ++b) s += S[b * 9 + t];
    tot[t] = s;
  }
  __syncthreads();
  if (t == 0) {
    int s = 0;
    for (int i = 0; i < 9; ++i) { ebase[i] = s; s += tot[i]; }
  }
  __syncthreads();
  if (t < 9) {
    int off = ebase[t];
    for (int b = 0; b < NSB; ++b) { int c = S[b * 9 + t]; S[b * 9 + t] = off; off += c; }
  }
  __syncthreads();
  for (int i = t; i < NSB * 9; i += 512) bh[i] = S[i];
}

__global__ void scatter_sorted(const float* __restrict__ zf, const int* __restrict__ bh,
                               int* __restrict__ perm, int B) {
  __shared__ int off[9];
  int t = threadIdx.x;
  if (t < 9) off[t] = bh[blockIdx.x * 9 + t];
  __syncthreads();
  int r = blockIdx.x * 512 + t;
  if (r < B) {
    int nf = min(max((int)floorf(zf[r] * 8.0f), 0), 8);
    int pos = atomicAdd(&off[nf], 1);
    perm[pos] = r;
  }
}

// ---------------------------------------------------------------------------
// Main kernel: register-resident activation chain, 4 waves x 32 rows.
// W2/W3 streamed as 8KB half-slices through a 4-buffer LDS ring with counted
// vmcnt(4). sched_group_barrier pins a DS_READ:MFMA 1:2 interleave in every
// MFMA loop so at most ~2 weight-fragment temps are live (round-6 hoisted
// all 16 -> 64 VGPRs -> spill: 487MB FETCH / 228MB WRITE of scratch).
// ---------------------------------------------------------------------------
__global__ __attribute__((amdgpu_flat_work_group_size(256, 256)))
__attribute__((amdgpu_waves_per_eu(2, 2))) void pinn_main(
    const float* __restrict__ sdz, const float* __restrict__ zf,
    const u16* __restrict__ Wf, const int* __restrict__ perm,
    const float* __restrict__ b1, const float* __restrict__ b2,
    const float* __restrict__ b3, const float* __restrict__ b4,
    float* __restrict__ out) {
  __shared__ __align__(16) u16 ringS[4][4096];   // 32 KB: 4 x 8KB half-slices
  __shared__ __align__(16) u16 W1s[8192];        // 16 KB
  __shared__ __align__(16) u16 W4s[4096];        // 8 KB
  __shared__ __align__(16) float biasS[784];     // b1|b2|b3|b4-padded
  __shared__ __align__(16) float stS[RPB * 4];
  __shared__ float qopS[RPB], dzS[RPB], fracS[RPB];
  __shared__ int nfS[RPB], rowG[RPB];

  const int t = threadIdx.x;
  const int lane = t & 63;
  const int q = lane >> 4;    // k-slot group / D row-block
  const int n = lane & 15;    // batch column within tile
  const int wv = t >> 6;      // 0..3
  const int rb = wv * 32;     // wave's first block-local row

  if (t < RPB) {
    int rg = perm[blockIdx.x * RPB + t];
    rowG[t] = rg;
    const float* p = sdz + (size_t)rg * 6;
    stS[t * 4 + 0] = p[0]; stS[t * 4 + 1] = p[1];
    stS[t * 4 + 2] = p[2]; stS[t * 4 + 3] = p[3];
    qopS[t] = p[4];
    dzS[t] = p[5] * 0.125f;
    float cs = zf[rg] * 8.0f;
    float nfl = floorf(cs);
    nfS[t] = (int)nfl;
    fracS[t] = cs - nfl;
  }
  biasS[t] = b1[t]; biasS[256 + t] = b2[t]; biasS[512 + t] = b3[t];
  if (t < 16) biasS[768 + t] = (t < 4) ? b4[t] : 0.0f;
  // stage W1 (16 chunks) and W4 (8 chunks); drained by the __syncthreads below
#pragma unroll
  for (int c = 0; c < 4; ++c)
    gld16(Wf + W1F + (c * 4 + wv) * 512 + lane * 8, &W1s[(c * 4 + wv) * 512]);
#pragma unroll
  for (int c = 0; c < 2; ++c)
    gld16(Wf + W4F + (c * 4 + wv) * 512 + lane * 8, &W4s[(c * 4 + wv) * 512]);
  __syncthreads();
  const int maxnf = nfS[RPB - 1];   // rows sorted by n_full

  f32x4 acc[16][2];
  v8s bact[8][2];

  // ---- ring pipeline: phase index ap; [layer:1][ks:3][h:1] = ap mod 32 ----
#define ISSUE_HALF(AP)                                                        \
  do {                                                                        \
    int p_ = (AP) & 31;                                                       \
    int off_ = ((p_ >> 4) ? W3F : W2F) + ((p_ >> 1) & 7) * 8192 + (p_ & 1) * 4096; \
    u16* dst_ = &ringS[(AP) & 3][0];                                          \
    gld16(Wf + off_ + (2 * wv) * 512 + lane * 8, dst_ + (2 * wv) * 512);      \
    gld16(Wf + off_ + (2 * wv + 1) * 512 + lane * 8, dst_ + (2 * wv + 1) * 512); \
  } while (0)

  int ap = 0;
  ISSUE_HALF(ap);
  ISSUE_HALF(ap + 1);

#define PACK_BACT()                                              \
  do {                                                           \
    _Pragma("unroll") for (int ks = 0; ks < 8; ++ks) {           \
      _Pragma("unroll") for (int nt = 0; nt < 2; ++nt) {         \
        f32x4 a0 = silu4(acc[2 * ks][nt]);                       \
        f32x4 a1 = silu4(acc[2 * ks + 1][nt]);                   \
        union { int4 i; v8s s; } u_;                             \
        u_.i.x = (int)pk2(a0[0], a0[1]);                         \
        u_.i.y = (int)pk2(a0[2], a0[3]);                         \
        u_.i.z = (int)pk2(a1[0], a1[1]);                         \
        u_.i.w = (int)pk2(a1[2], a1[3]);                         \
        bact[ks][nt] = u_.s;                                     \
      }                                                          \
    }                                                            \
  } while (0)

  for (int ev = 0; ev <= maxnf; ++ev) {
    const bool partial = (ev == maxnf);

    // ---- build layer-1 B-fragments (hi/lo split of [state,qop,dz]) ----
    v8s b1f[2];
#pragma unroll
    for (int nt = 0; nt < 2; ++nt) {
      const int row = rb + nt * 16 + n;
      const float4 st = *(const float4*)&stS[row * 4];
      const float qop = qopS[row];
      const float dzv = partial ? fracS[row] * dzS[row] : dzS[row];
      u32 h01 = pk2(st.x, st.y), h23 = pk2(st.z, st.w), hqd = pk2(qop, dzv);
      float l0 = st.x - bfu(h01, 0), l1 = st.y - bfu(h01, 1);
      float l2 = st.z - bfu(h23, 0), l3 = st.w - bfu(h23, 1);
      float lq = qop - bfu(hqd, 0), ld = dzv - bfu(hqd, 1);
      u32 w0 = 0, w1 = 0;
      if (q == 0) { w0 = h01; w1 = h23; }
      else if (q == 1) { w0 = hqd; w1 = pk2(l0, l1); }
      else if (q == 2) { w0 = pk2(l2, l3); w1 = pk2(lq, ld); }
      union { int4 i; v8s s; } u_;
      u_.i.x = (int)w0; u_.i.y = (int)w1; u_.i.z = 0; u_.i.w = 0;
      b1f[nt] = u_.s;
    }

    // ---- L1: acc = W1^T @ x + b1 (bias as accumulator init) ----
#pragma unroll
    for (int mt = 0; mt < 16; ++mt) {
      const v8s w = *(const v8s*)&W1s[mt * 512 + lane * 8];
      const float4 bb = *(const float4*)&biasS[mt * 16 + q * 4];
      const f32x4 binit = {bb.x, bb.y, bb.z, bb.w};
#pragma unroll
      for (int nt = 0; nt < 2; ++nt)
        acc[mt][nt] = MFMA(w, b1f[nt], binit);
      SGB(M_DS, 2, 0);    // w + bias
      SGB(M_MFMA, 2, 0);  // keep <=1 w-temp live
    }
    PACK_BACT();

    // ---- L2, L3: 256x256, counted-vmcnt ring-pipelined half-slices ----
#pragma unroll
    for (int layer = 0; layer < 2; ++layer) {
      const int Lb = (layer == 0) ? 256 : 512;
#pragma unroll
      for (int mt = 0; mt < 16; ++mt) {
        const float4 bb = *(const float4*)&biasS[Lb + mt * 16 + q * 4];
        const f32x4 binit = {bb.x, bb.y, bb.z, bb.w};
        acc[mt][0] = binit;
        acc[mt][1] = binit;
      }
#pragma unroll
      for (int ks = 0; ks < 8; ++ks) {
#pragma unroll
        for (int h = 0; h < 2; ++h) {
          ISSUE_HALF(ap + 2);                      // 2 gld16 -> in flight
          asm volatile("s_waitcnt vmcnt(4)" ::: "memory");  // own slice-ap loads done
          __builtin_amdgcn_sched_barrier(0);
          __builtin_amdgcn_s_barrier();            // publish; NO vmcnt(0) drain
          __builtin_amdgcn_sched_barrier(0);
          asm volatile("" ::: "memory");
          const u16* buf = &ringS[ap & 3][0];
          __builtin_amdgcn_s_setprio(1);
#pragma unroll
          for (int i = 0; i < 8; ++i) {
            const v8s w = *(const v8s*)&buf[i * 512 + lane * 8];
            acc[h * 8 + i][0] = MFMA(w, bact[ks][0], acc[h * 8 + i][0]);
            acc[h * 8 + i][1] = MFMA(w, bact[ks][1], acc[h * 8 + i][1]);
            SGB(M_DS, 1, 0);    // ds_read_b128 (w)
            SGB(M_MFMA, 2, 0);  // its 2 MFMAs -> <=2 w-temps live
          }
          __builtin_amdgcn_s_setprio(0);
          ++ap;
        }
      }
      PACK_BACT();
    }

    // ---- L4 + masked state update (stS rows are wave-private) ----
    {
      const float4 bb = *(const float4*)&biasS[768 + q * 4];
      f32x4 a4[2];
      a4[0] = (f32x4){bb.x, bb.y, bb.z, bb.w};
      a4[1] = a4[0];
#pragma unroll
      for (int ks = 0; ks < 8; ++ks) {
        const v8s w = *(const v8s*)&W4s[ks * 512 + lane * 8];
        a4[0] = MFMA(w, bact[ks][0], a4[0]);
        a4[1] = MFMA(w, bact[ks][1], a4[1]);
        SGB(M_DS, 1, 0);
        SGB(M_MFMA, 2, 0);
      }
      if (q == 0) {
#pragma unroll
        for (int nt = 0; nt < 2; ++nt) {
          const int row = rb + nt * 16 + n;
          const bool act = partial ? (fracS[row] > 1e-6f) : (nfS[row] > ev);
          if (act) {
            float4 cur = *(float4*)&stS[row * 4];
            cur.x += a4[nt][0]; cur.y += a4[nt][1];
            cur.z += a4[nt][2]; cur.w += a4[nt][3];
            *(float4*)&stS[row * 4] = cur;
          }
        }
      }
    }
  }
  __syncthreads();   // drains remaining ring prefetches + stS visibility

  // scattered output write (16B per row, rows permuted)
  for (int i = t; i < RPB * 4; i += THREADS)
    out[(size_t)rowG[i >> 2] * 4 + (i & 3)] = stS[i];
}

extern "C" void kernel_launch(void* const* d_in, const int* in_sizes, int n_in,
                              void* d_out, int out_size, void* d_ws, size_t ws_size,
                              hipStream_t stream) {
  const float* sdz = (const float*)d_in[0];
  const float* zfr = (const float*)d_in[1];
  const float* W1 = (const float*)d_in[2];
  const float* b1 = (const float*)d_in[3];
  const float* W2 = (const float*)d_in[4];
  const float* b2 = (const float*)d_in[5];
  const float* W3 = (const float*)d_in[6];
  const float* b3 = (const float*)d_in[7];
  const float* W4 = (const float*)d_in[8];
  const float* b4 = (const float*)d_in[9];

  char* ws = (char*)d_ws;
  u16* Wf = (u16*)ws;
  int* bh = (int*)(ws + BH_OFF);
  int* perm = (int*)(ws + PERM_OFF);

  const int B = in_sizes[1];   // 262144

  prep_weights<<<(TOTW + 255) / 256, 256, 0, stream>>>(W1, W2, W3, W4, Wf);
  hist_blocks<<<NSB, 512, 0, stream>>>(zfr, bh, B);
  scan_offsets<<<1, 512, 0, stream>>>(bh);
  scatter_sorted<<<NSB, 512, 0, stream>>>(zfr, bh, perm, B);
  pinn_main<<<B / RPB, THREADS, 0, stream>>>(sdz, zfr, Wf, perm, b1, b2, b3, b4,
                                             (float*)d_out);
}

// Round 9
// 549.775 us; speedup vs baseline: 1.5483x; 1.5483x over previous
//
#include <hip/hip_runtime.h>

typedef unsigned short u16;
typedef unsigned int u32;
typedef __attribute__((ext_vector_type(8))) short v8s;
typedef __attribute__((ext_vector_type(4))) float f32x4;

#define RPB 64             // rows per block (4 waves x 16 rows)
#define THREADS 256
#define NSB 512            // sort blocks (512 x 512 threads = 262144)
// u16 offsets inside Wf
#define W1F 0
#define W2F 8192
#define W3F 73728
#define W4F 139264
#define TOTW 143360
// workspace byte offsets
#define BH_OFF 286720      // blockHist: NSB*9*4 = 18432 B
#define PERM_OFF 305152    // perm: B*4

#define MFMA(w, b, c) __builtin_amdgcn_mfma_f32_16x16x32_bf16((w), (b), (c), 0, 0, 0)

typedef __attribute__((address_space(1))) const unsigned int gu32;
typedef __attribute__((address_space(3))) unsigned int su32;
__device__ __forceinline__ void gld16(const u16* g, u16* l) {
  __builtin_amdgcn_global_load_lds((gu32*)g, (su32*)l, 16, 0, 0);
}

__device__ __forceinline__ u32 pk2(float a, float b) {
  u32 r;
  asm("v_cvt_pk_bf16_f32 %0, %1, %2" : "=v"(r) : "v"(a), "v"(b));
  return r;
}
__device__ __forceinline__ float bfu(u32 w, int hi) {   // bf16 half -> f32
  return __uint_as_float(hi ? (w & 0xffff0000u) : (w << 16));
}
__device__ __forceinline__ f32x4 silu4(f32x4 v) {
  f32x4 r;
#pragma unroll
  for (int i = 0; i < 4; ++i) r[i] = v[i] * __builtin_amdgcn_rcpf(1.0f + __expf(-v[i]));
  return r;
}

// ---------------------------------------------------------------------------
// Weight prep: bf16, A-fragment order (lane l holds A[m=l&15][k-slot q*8+j]),
// with the k-slot permutation  slot(q,j) <-> feature f = 32ks+16*(j>>2)+4q+(j&3).
// W1: K padded 12->32 (rows 6..11 duplicate 0..5 for the hi/lo input split).
// W4: out-features padded 4->16. W2/W3 stored slice-major: (ks*16+mt)*512.
// ---------------------------------------------------------------------------
__global__ void prep_weights(const float* __restrict__ W1, const float* __restrict__ W2,
                             const float* __restrict__ W3, const float* __restrict__ W4,
                             u16* __restrict__ Wf) {
  int e = blockIdx.x * 256 + threadIdx.x;
  if (e >= TOTW) return;
  float val = 0.0f;
  if (e < W2F) {
    int mt = e >> 9, idx = e & 511, l = idx >> 3, j = idx & 7;
    int q = l >> 4, m = l & 15;
    int f = 16 * (j >> 2) + 4 * q + (j & 3);
    int col = mt * 16 + m;
    val = (f < 6) ? W1[f * 256 + col] : ((f < 12) ? W1[(f - 6) * 256 + col] : 0.0f);
  } else if (e < W3F) {
    int e2 = e - W2F, blk = e2 >> 9, idx = e2 & 511, l = idx >> 3, j = idx & 7;
    int ks = blk >> 4, mt = blk & 15, q = l >> 4, m = l & 15;
    int f = 32 * ks + 16 * (j >> 2) + 4 * q + (j & 3);
    val = W2[f * 256 + mt * 16 + m];
  } else if (e < W4F) {
    int e2 = e - W3F, blk = e2 >> 9, idx = e2 & 511, l = idx >> 3, j = idx & 7;
    int ks = blk >> 4, mt = blk & 15, q = l >> 4, m = l & 15;
    int f = 32 * ks + 16 * (j >> 2) + 4 * q + (j & 3);
    val = W3[f * 256 + mt * 16 + m];
  } else {
    int e2 = e - W4F, ks = e2 >> 9, idx = e2 & 511, l = idx >> 3, j = idx & 7;
    int q = l >> 4, m = l & 15;
    int f = 32 * ks + 16 * (j >> 2) + 4 * q + (j & 3);
    val = (m < 4) ? W4[f * 4 + m] : 0.0f;
  }
  Wf[e] = (u16)pk2(val, val);
}

// ------------------ counting sort by n_full (LDS-local, no global atomics) --
__global__ void hist_blocks(const float* __restrict__ zf, int* __restrict__ bh, int B) {
  __shared__ int h[9];
  int t = threadIdx.x;
  if (t < 9) h[t] = 0;
  __syncthreads();
  int r = blockIdx.x * 512 + t;
  if (r < B) {
    int nf = min(max((int)floorf(zf[r] * 8.0f), 0), 8);
    atomicAdd(&h[nf], 1);
  }
  __syncthreads();
  if (t < 9) bh[blockIdx.x * 9 + t] = h[t];
}

__global__ void scan_offsets(int* __restrict__ bh) {
  __shared__ int S[NSB * 9];
  __shared__ int tot[9], ebase[9];
  int t = threadIdx.x;
  for (int i = t; i < NSB * 9; i += 512) S[i] = bh[i];
  __syncthreads();
  if (t < 9) {
    int s = 0;
    for (int b = 0; b < NSB; ++b) s += S[b * 9 + t];
    tot[t] = s;
  }
  __syncthreads();
  if (t == 0) {
    int s = 0;
    for (int i = 0; i < 9; ++i) { ebase[i] = s; s += tot[i]; }
  }
  __syncthreads();
  if (t < 9) {
    int off = ebase[t];
    for (int b = 0; b < NSB; ++b) { int c = S[b * 9 + t]; S[b * 9 + t] = off; off += c; }
  }
  __syncthreads();
  for (int i = t; i < NSB * 9; i += 512) bh[i] = S[i];
}

__global__ void scatter_sorted(const float* __restrict__ zf, const int* __restrict__ bh,
                               int* __restrict__ perm, int B) {
  __shared__ int off[9];
  int t = threadIdx.x;
  if (t < 9) off[t] = bh[blockIdx.x * 9 + t];
  __syncthreads();
  int r = blockIdx.x * 512 + t;
  if (r < B) {
    int nf = min(max((int)floorf(zf[r] * 8.0f), 0), 8);
    int pos = atomicAdd(&off[nf], 1);
    perm[pos] = r;
  }
}

// ---------------------------------------------------------------------------
// Main kernel: register-resident activation chain, 4 waves x 16 rows (nt=1).
// Live set shrunk to fit 128 arch VGPRs with margin: acc[16] (64, AGPR-
// eligible), bact[8] (32), b1f (4). Rounds 3-7 (32 rows/wave, 192+ live)
// spilled ~230MB scratch/dispatch regardless of launch-bounds spelling.
// W2/W3 stream through a 4-buffer 8KB-half-slice LDS ring, counted vmcnt(4).
// ---------------------------------------------------------------------------
__global__ __attribute__((amdgpu_flat_work_group_size(256, 256)))
__attribute__((amdgpu_waves_per_eu(2, 2))) void pinn_main(
    const float* __restrict__ sdz, const float* __restrict__ zf,
    const u16* __restrict__ Wf, const int* __restrict__ perm,
    const float* __restrict__ b1, const float* __restrict__ b2,
    const float* __restrict__ b3, const float* __restrict__ b4,
    float* __restrict__ out) {
  __shared__ __align__(16) u16 ringS[4][4096];   // 32 KB: 4 x 8KB half-slices
  __shared__ __align__(16) u16 W1s[8192];        // 16 KB
  __shared__ __align__(16) u16 W4s[4096];        // 8 KB
  __shared__ __align__(16) float biasS[784];     // b1|b2|b3|b4-padded
  __shared__ __align__(16) float stS[RPB * 4];
  __shared__ float qopS[RPB], dzS[RPB], fracS[RPB];
  __shared__ int nfS[RPB], rowG[RPB];

  const int t = threadIdx.x;
  const int lane = t & 63;
  const int q = lane >> 4;    // k-slot group / D row-block
  const int n = lane & 15;    // batch column within tile
  const int wv = t >> 6;      // 0..3
  const int rb = wv * 16;     // wave's first block-local row

  if (t < RPB) {
    int rg = perm[blockIdx.x * RPB + t];
    rowG[t] = rg;
    const float* p = sdz + (size_t)rg * 6;
    stS[t * 4 + 0] = p[0]; stS[t * 4 + 1] = p[1];
    stS[t * 4 + 2] = p[2]; stS[t * 4 + 3] = p[3];
    qopS[t] = p[4];
    dzS[t] = p[5] * 0.125f;
    float cs = zf[rg] * 8.0f;
    float nfl = floorf(cs);
    nfS[t] = (int)nfl;
    fracS[t] = cs - nfl;
  }
  biasS[t] = b1[t]; biasS[256 + t] = b2[t]; biasS[512 + t] = b3[t];
  if (t < 16) biasS[768 + t] = (t < 4) ? b4[t] : 0.0f;
  // stage W1 (16 chunks) and W4 (8 chunks); drained by the __syncthreads below
#pragma unroll
  for (int c = 0; c < 4; ++c)
    gld16(Wf + W1F + (c * 4 + wv) * 512 + lane * 8, &W1s[(c * 4 + wv) * 512]);
#pragma unroll
  for (int c = 0; c < 2; ++c)
    gld16(Wf + W4F + (c * 4 + wv) * 512 + lane * 8, &W4s[(c * 4 + wv) * 512]);
  __syncthreads();
  const int maxnf = nfS[RPB - 1];   // rows sorted by n_full

  f32x4 acc[16];
  v8s bact[8];

  // ---- ring pipeline: phase index ap; [layer:1][ks:3][h:1] = ap mod 32 ----
#define ISSUE_HALF(AP)                                                        \
  do {                                                                        \
    int p_ = (AP) & 31;                                                       \
    int off_ = ((p_ >> 4) ? W3F : W2F) + ((p_ >> 1) & 7) * 8192 + (p_ & 1) * 4096; \
    u16* dst_ = &ringS[(AP) & 3][0];                                          \
    gld16(Wf + off_ + (2 * wv) * 512 + lane * 8, dst_ + (2 * wv) * 512);      \
    gld16(Wf + off_ + (2 * wv + 1) * 512 + lane * 8, dst_ + (2 * wv + 1) * 512); \
  } while (0)

  int ap = 0;
  ISSUE_HALF(ap);
  ISSUE_HALF(ap + 1);

#define PACK_BACT()                                              \
  do {                                                           \
    _Pragma("unroll") for (int ks = 0; ks < 8; ++ks) {           \
      f32x4 a0 = silu4(acc[2 * ks]);                             \
      f32x4 a1 = silu4(acc[2 * ks + 1]);                         \
      union { int4 i; v8s s; } u_;                               \
      u_.i.x = (int)pk2(a0[0], a0[1]);                           \
      u_.i.y = (int)pk2(a0[2], a0[3]);                           \
      u_.i.z = (int)pk2(a1[0], a1[1]);                           \
      u_.i.w = (int)pk2(a1[2], a1[3]);                           \
      bact[ks] = u_.s;                                           \
    }                                                            \
  } while (0)

  for (int ev = 0; ev <= maxnf; ++ev) {
    const bool partial = (ev == maxnf);

    // ---- build layer-1 B-fragment (hi/lo split of [state,qop,dz]) ----
    v8s b1f;
    {
      const int row = rb + n;
      const float4 st = *(const float4*)&stS[row * 4];
      const float qop = qopS[row];
      const float dzv = partial ? fracS[row] * dzS[row] : dzS[row];
      u32 h01 = pk2(st.x, st.y), h23 = pk2(st.z, st.w), hqd = pk2(qop, dzv);
      float l0 = st.x - bfu(h01, 0), l1 = st.y - bfu(h01, 1);
      float l2 = st.z - bfu(h23, 0), l3 = st.w - bfu(h23, 1);
      float lq = qop - bfu(hqd, 0), ld = dzv - bfu(hqd, 1);
      u32 w0 = 0, w1 = 0;
      if (q == 0) { w0 = h01; w1 = h23; }
      else if (q == 1) { w0 = hqd; w1 = pk2(l0, l1); }
      else if (q == 2) { w0 = pk2(l2, l3); w1 = pk2(lq, ld); }
      union { int4 i; v8s s; } u_;
      u_.i.x = (int)w0; u_.i.y = (int)w1; u_.i.z = 0; u_.i.w = 0;
      b1f = u_.s;
    }

    // ---- L1: acc = W1^T @ x + b1 (bias as accumulator init) ----
#pragma unroll
    for (int mt = 0; mt < 16; ++mt) {
      const v8s w = *(const v8s*)&W1s[mt * 512 + lane * 8];
      const float4 bb = *(const float4*)&biasS[mt * 16 + q * 4];
      const f32x4 binit = {bb.x, bb.y, bb.z, bb.w};
      acc[mt] = MFMA(w, b1f, binit);
    }
    PACK_BACT();

    // ---- L2, L3: 256x256, counted-vmcnt ring-pipelined half-slices ----
#pragma unroll
    for (int layer = 0; layer < 2; ++layer) {
      const int Lb = (layer == 0) ? 256 : 512;
#pragma unroll
      for (int mt = 0; mt < 16; ++mt) {
        const float4 bb = *(const float4*)&biasS[Lb + mt * 16 + q * 4];
        const f32x4 binit = {bb.x, bb.y, bb.z, bb.w};
        acc[mt] = binit;
      }
#pragma unroll
      for (int ks = 0; ks < 8; ++ks) {
#pragma unroll
        for (int h = 0; h < 2; ++h) {
          ISSUE_HALF(ap + 2);                      // 2 gld16 -> in flight
          asm volatile("s_waitcnt vmcnt(4)" ::: "memory");  // own slice-ap loads done
          __builtin_amdgcn_sched_barrier(0);
          __builtin_amdgcn_s_barrier();            // publish; NO vmcnt(0) drain
          __builtin_amdgcn_sched_barrier(0);
          asm volatile("" ::: "memory");
          const u16* buf = &ringS[ap & 3][0];
          __builtin_amdgcn_s_setprio(1);
#pragma unroll
          for (int i = 0; i < 8; ++i) {
            const v8s w = *(const v8s*)&buf[i * 512 + lane * 8];
            acc[h * 8 + i] = MFMA(w, bact[ks], acc[h * 8 + i]);
          }
          __builtin_amdgcn_s_setprio(0);
          ++ap;
        }
      }
      PACK_BACT();
    }

    // ---- L4 + masked state update (stS rows are wave-private) ----
    {
      const float4 bb = *(const float4*)&biasS[768 + q * 4];
      f32x4 a4 = {bb.x, bb.y, bb.z, bb.w};
#pragma unroll
      for (int ks = 0; ks < 8; ++ks) {
        const v8s w = *(const v8s*)&W4s[ks * 512 + lane * 8];
        a4 = MFMA(w, bact[ks], a4);
      }
      if (q == 0) {
        const int row = rb + n;
        const bool act = partial ? (fracS[row] > 1e-6f) : (nfS[row] > ev);
        if (act) {
          float4 cur = *(float4*)&stS[row * 4];
          cur.x += a4[0]; cur.y += a4[1];
          cur.z += a4[2]; cur.w += a4[3];
          *(float4*)&stS[row * 4] = cur;
        }
      }
    }
  }
  __syncthreads();   // drains remaining ring prefetches + stS visibility

  // scattered output write (16B per row, rows permuted)
  {
    const int i = t;   // RPB*4 == THREADS
    out[(size_t)rowG[i >> 2] * 4 + (i & 3)] = stS[i];
  }
}

extern "C" void kernel_launch(void* const* d_in, const int* in_sizes, int n_in,
                              void* d_out, int out_size, void* d_ws, size_t ws_size,
                              hipStream_t stream) {
  const float* sdz = (const float*)d_in[0];
  const float* zfr = (const float*)d_in[1];
  const float* W1 = (const float*)d_in[2];
  const float* b1 = (const float*)d_in[3];
  const float* W2 = (const float*)d_in[4];
  const float* b2 = (const float*)d_in[5];
  const float* W3 = (const float*)d_in[6];
  const float* b3 = (const float*)d_in[7];
  const float* W4 = (const float*)d_in[8];
  const float* b4 = (const float*)d_in[9];

  char* ws = (char*)d_ws;
  u16* Wf = (u16*)ws;
  int* bh = (int*)(ws + BH_OFF);
  int* perm = (int*)(ws + PERM_OFF);

  const int B = in_sizes[1];   // 262144

  prep_weights<<<(TOTW + 255) / 256, 256, 0, stream>>>(W1, W2, W3, W4, Wf);
  hist_blocks<<<NSB, 512, 0, stream>>>(zfr, bh, B);
  scan_offsets<<<1, 512, 0, stream>>>(bh);
  scatter_sorted<<<NSB, 512, 0, stream>>>(zfr, bh, perm, B);
  pinn_main<<<B / RPB, THREADS, 0, stream>>>(sdz, zfr, Wf, perm, b1, b2, b3, b4,
                                             (float*)d_out);
}